// Round 1
// baseline (1490.766 us; speedup 1.0000x reference)
//
#include <hip/hip_runtime.h>

#define EPSN 1e-12f

// ---------------------------------------------------------------------------
// Per-window 64x64 matmul: Out[o][p] = sum_c W[o][c] * In[c][p]
// W: row-major 64x64 (global or LDS). In/Out: LDS [64][64].
// Thread tile: 2 output rows (o0,o0+1) x 8 pixels (p0..p0+7).
// ---------------------------------------------------------------------------
static __device__ __forceinline__ void mm64(const float* __restrict__ W,
                                            const float* __restrict__ In,
                                            float* __restrict__ Out, int t)
{
    const int o0 = (t >> 3) << 1;   // 0,2,...,62
    const int p0 = (t & 7) << 3;    // 0,8,...,56
    float acc0[8], acc1[8];
#pragma unroll
    for (int p = 0; p < 8; ++p) { acc0[p] = 0.f; acc1[p] = 0.f; }
    const float* w0 = W + o0 * 64;
    const float* w1 = w0 + 64;
    for (int c = 0; c < 64; c += 4) {
        float4 wa4 = *(const float4*)(w0 + c);
        float4 wb4 = *(const float4*)(w1 + c);
        float wa[4] = {wa4.x, wa4.y, wa4.z, wa4.w};
        float wb[4] = {wb4.x, wb4.y, wb4.z, wb4.w};
#pragma unroll
        for (int k = 0; k < 4; ++k) {
            float4 xa = *(const float4*)(In + (c + k) * 64 + p0);
            float4 xb = *(const float4*)(In + (c + k) * 64 + p0 + 4);
            float xr[8] = {xa.x, xa.y, xa.z, xa.w, xb.x, xb.y, xb.z, xb.w};
#pragma unroll
            for (int p = 0; p < 8; ++p) {
                acc0[p] = fmaf(wa[k], xr[p], acc0[p]);
                acc1[p] = fmaf(wb[k], xr[p], acc1[p]);
            }
        }
    }
    float* op0 = Out + o0 * 64 + p0;
    float* op1 = op0 + 64;
    *(float4*)op0       = make_float4(acc0[0], acc0[1], acc0[2], acc0[3]);
    *(float4*)(op0 + 4) = make_float4(acc0[4], acc0[5], acc0[6], acc0[7]);
    *(float4*)op1       = make_float4(acc1[0], acc1[1], acc1[2], acc1[3]);
    *(float4*)(op1 + 4) = make_float4(acc1[4], acc1[5], acc1[6], acc1[7]);
}

// ---------------------------------------------------------------------------
// Depthwise 3x3, zero pad, on per-channel 8x8 tiles stored row-major in LDS.
// Thread: channel c = t>>2, output rows r0, r0+1.
// TR=false: write Out row-major [c][p].  TR=true: write transposed [p][c].
// wg: global, 9 floats per channel at wg + c*9.
// ---------------------------------------------------------------------------
template <bool TR>
static __device__ __forceinline__ void dw3x3(const float* __restrict__ T,
                                             const float* __restrict__ wg,
                                             float* __restrict__ Out, int t)
{
    const int c  = t >> 2;
    const int r0 = (t & 3) << 1;
    float w[9];
#pragma unroll
    for (int k = 0; k < 9; ++k) w[k] = wg[c * 9 + k];
    float in[4][10];
#pragma unroll
    for (int r = 0; r < 4; ++r) {
        const int rr = r0 - 1 + r;
        in[r][0] = 0.f; in[r][9] = 0.f;
        if (rr >= 0 && rr < 8) {
            float4 a = *(const float4*)(T + c * 64 + rr * 8);
            float4 b = *(const float4*)(T + c * 64 + rr * 8 + 4);
            in[r][1] = a.x; in[r][2] = a.y; in[r][3] = a.z; in[r][4] = a.w;
            in[r][5] = b.x; in[r][6] = b.y; in[r][7] = b.z; in[r][8] = b.w;
        } else {
#pragma unroll
            for (int j = 1; j < 9; ++j) in[r][j] = 0.f;
        }
    }
#pragma unroll
    for (int rr = 0; rr < 2; ++rr) {
        float o[8];
#pragma unroll
        for (int j = 0; j < 8; ++j) {
            float s = 0.f;
            s = fmaf(w[0], in[rr][j],         s);
            s = fmaf(w[1], in[rr][j + 1],     s);
            s = fmaf(w[2], in[rr][j + 2],     s);
            s = fmaf(w[3], in[rr + 1][j],     s);
            s = fmaf(w[4], in[rr + 1][j + 1], s);
            s = fmaf(w[5], in[rr + 1][j + 2], s);
            s = fmaf(w[6], in[rr + 2][j],     s);
            s = fmaf(w[7], in[rr + 2][j + 1], s);
            s = fmaf(w[8], in[rr + 2][j + 2], s);
            o[j] = s;
        }
        if (TR) {
            const int p = (r0 + rr) << 3;
#pragma unroll
            for (int j = 0; j < 8; ++j) Out[(p + j) * 64 + c] = o[j];
        } else {
            float* d = Out + c * 64 + ((r0 + rr) << 3);
            *(float4*)d       = make_float4(o[0], o[1], o[2], o[3]);
            *(float4*)(d + 4) = make_float4(o[4], o[5], o[6], o[7]);
        }
    }
}

// L2-normalize each row of row-major [64][64] LDS matrix (4 threads/row).
static __device__ __forceinline__ void l2norm_rows(float* Q, int t)
{
    const int r = t >> 2, part = (t & 3) << 4;
    float v[16];
#pragma unroll
    for (int k = 0; k < 16; k += 4) {
        float4 a = *(const float4*)(Q + r * 64 + part + k);
        v[k] = a.x; v[k + 1] = a.y; v[k + 2] = a.z; v[k + 3] = a.w;
    }
    float s = 0.f;
#pragma unroll
    for (int k = 0; k < 16; ++k) s = fmaf(v[k], v[k], s);
    s += __shfl_xor(s, 1);
    s += __shfl_xor(s, 2);
    const float nrm = fmaxf(sqrtf(s), EPSN);
#pragma unroll
    for (int k = 0; k < 16; ++k) v[k] /= nrm;
#pragma unroll
    for (int k = 0; k < 16; k += 4)
        *(float4*)(Q + r * 64 + part + k) = make_float4(v[k], v[k+1], v[k+2], v[k+3]);
}

// L2-normalize each COLUMN of [64][64] LDS matrix (for K stored transposed).
static __device__ __forceinline__ void l2norm_cols(float* KT, int t)
{
    const int b = t >> 2, part = (t & 3) << 4;
    float v[16];
#pragma unroll
    for (int k = 0; k < 16; ++k) v[k] = KT[(part + k) * 64 + b];
    float s = 0.f;
#pragma unroll
    for (int k = 0; k < 16; ++k) s = fmaf(v[k], v[k], s);
    s += __shfl_xor(s, 1);
    s += __shfl_xor(s, 2);
    const float nrm = fmaxf(sqrtf(s), EPSN);
#pragma unroll
    for (int k = 0; k < 16; ++k) KT[(part + k) * 64 + b] = v[k] / nrm;
}

// softmax over each row of row-major [64][64] LDS matrix of logits/temp.
static __device__ __forceinline__ void softmax_rows(float* S, float tempv, int t)
{
    const int r = t >> 2, part = (t & 3) << 4;
    float v[16];
#pragma unroll
    for (int k = 0; k < 16; k += 4) {
        float4 a = *(const float4*)(S + r * 64 + part + k);
        v[k] = a.x; v[k + 1] = a.y; v[k + 2] = a.z; v[k + 3] = a.w;
    }
#pragma unroll
    for (int k = 0; k < 16; ++k) v[k] = v[k] / tempv;
    float mx = v[0];
#pragma unroll
    for (int k = 1; k < 16; ++k) mx = fmaxf(mx, v[k]);
    mx = fmaxf(mx, __shfl_xor(mx, 1));
    mx = fmaxf(mx, __shfl_xor(mx, 2));
    float s = 0.f;
#pragma unroll
    for (int k = 0; k < 16; ++k) { v[k] = expf(v[k] - mx); s += v[k]; }
    s += __shfl_xor(s, 1);
    s += __shfl_xor(s, 2);
#pragma unroll
    for (int k = 0; k < 16; ++k) v[k] /= s;
#pragma unroll
    for (int k = 0; k < 16; k += 4)
        *(float4*)(S + r * 64 + part + k) = make_float4(v[k], v[k+1], v[k+2], v[k+3]);
}

// Dense 3x3 "proj" conv over the 64 tiles: thread -> out channel o = t>>2,
// output rows r0, r0+1. Result left in outv.
static __device__ __forceinline__ void proj3x3(const float* __restrict__ O,
                                               const float* __restrict__ W,
                                               int t, float outv[2][8])
{
    const int o  = t >> 2;
    const int r0 = (t & 3) << 1;
    float acc[2][8];
#pragma unroll
    for (int rr = 0; rr < 2; ++rr)
#pragma unroll
        for (int j = 0; j < 8; ++j) acc[rr][j] = 0.f;

    float wc[9];
#pragma unroll
    for (int k = 0; k < 9; ++k) wc[k] = W[o * 576 + k];

    for (int c = 0; c < 64; ++c) {
        float wn[9];
        if (c < 63) {
#pragma unroll
            for (int k = 0; k < 9; ++k) wn[k] = W[o * 576 + (c + 1) * 9 + k];
        } else {
#pragma unroll
            for (int k = 0; k < 9; ++k) wn[k] = 0.f;
        }
        float in[4][10];
#pragma unroll
        for (int r = 0; r < 4; ++r) {
            const int rr = r0 - 1 + r;
            in[r][0] = 0.f; in[r][9] = 0.f;
            if (rr >= 0 && rr < 8) {
                float4 a = *(const float4*)(O + c * 64 + rr * 8);
                float4 b = *(const float4*)(O + c * 64 + rr * 8 + 4);
                in[r][1] = a.x; in[r][2] = a.y; in[r][3] = a.z; in[r][4] = a.w;
                in[r][5] = b.x; in[r][6] = b.y; in[r][7] = b.z; in[r][8] = b.w;
            } else {
#pragma unroll
                for (int j = 1; j < 9; ++j) in[r][j] = 0.f;
            }
        }
#pragma unroll
        for (int rr = 0; rr < 2; ++rr)
#pragma unroll
            for (int j = 0; j < 8; ++j) {
                float s = acc[rr][j];
                s = fmaf(wc[0], in[rr][j],         s);
                s = fmaf(wc[1], in[rr][j + 1],     s);
                s = fmaf(wc[2], in[rr][j + 2],     s);
                s = fmaf(wc[3], in[rr + 1][j],     s);
                s = fmaf(wc[4], in[rr + 1][j + 1], s);
                s = fmaf(wc[5], in[rr + 1][j + 2], s);
                s = fmaf(wc[6], in[rr + 2][j],     s);
                s = fmaf(wc[7], in[rr + 2][j + 1], s);
                s = fmaf(wc[8], in[rr + 2][j + 2], s);
                acc[rr][j] = s;
            }
#pragma unroll
        for (int k = 0; k < 9; ++k) wc[k] = wn[k];
    }
#pragma unroll
    for (int rr = 0; rr < 2; ++rr)
#pragma unroll
        for (int j = 0; j < 8; ++j) outv[rr][j] = acc[rr][j];
}

// ---------------------------------------------------------------------------
// Branch 1: window n = contiguous 4096-float strip of x / x_f.
// mid gets branch-1 output in plain NCHW image layout.
// ---------------------------------------------------------------------------
__global__ __launch_bounds__(256, 2) void k1(
    const float* __restrict__ x, const float* __restrict__ xf,
    const float* __restrict__ temp_p,
    const float* __restrict__ qk_w, const float* __restrict__ qk_dw,
    const float* __restrict__ v_w, const float* __restrict__ v_dw,
    const float* __restrict__ proj_w,
    float* __restrict__ mid)
{
    __shared__ __align__(16) float B0[4096], B1[4096], B2[4096], B3[4096], B4[4096];
    const int n = blockIdx.x;
    const int t = threadIdx.x;
    const size_t base = (size_t)n << 12;

    {   // load x_f -> B0, x -> B1, converting strip(y',x') to V layout [c2][p]
        const int yp = t >> 4, xx0 = (t & 15) << 4;
        const float* gf = xf + base + yp * 256 + xx0;
        const float* gx = x + base + yp * 256 + xx0;
        const int c2b = (yp >> 3) << 5;
        const int ir  = (yp & 7) << 3;
#pragma unroll
        for (int k = 0; k < 4; ++k) {
            float4 a = *(const float4*)(gf + 4 * k);
            float4 b = *(const float4*)(gx + 4 * k);
            const int xx = xx0 + 4 * k;
            const int off = (c2b + (xx >> 3)) * 64 + ir + (xx & 7);
            *(float4*)(B0 + off) = a;
            *(float4*)(B1 + off) = b;
        }
    }
    __syncthreads();
    mm64(v_w, B1, B2, t);                    // tempV = Wv @ X
    __syncthreads();
    dw3x3<false>(B2, v_dw, B3, t);           // V  -> B3
    mm64(qk_w, B0, B1, t);                   // tempQ -> B1 (X dead)
    __syncthreads();
    dw3x3<false>(B1, qk_dw, B2, t);          // Q  -> B2 (tempV dead)
    mm64(qk_w + 64 * 64, B0, B4, t);         // tempK -> B4
    __syncthreads();
    dw3x3<true>(B4, qk_dw + 64 * 9, B1, t);  // K^T -> B1 (tempQ dead)
    l2norm_rows(B2, t);                      // normalize Q rows in place
    __syncthreads();
    l2norm_cols(B1, t);                      // normalize K (columns of K^T)
    __syncthreads();
    mm64(B2, B1, B0, t);                     // S = Q @ K^T -> B0 (Xf dead)
    __syncthreads();
    softmax_rows(B0, temp_p[0], t);          // A in place
    __syncthreads();
    mm64(B0, B3, B4, t);                     // O = A @ V -> B4 (tempK dead)
    __syncthreads();
    float pv[2][8];
    proj3x3(B4, proj_w, t, pv);
    {   // store to mid in NCHW image layout (window_reverse folded in)
        const int o = t >> 2, r0 = (t & 3) << 1;
        const int col = (o & 31) << 3;
#pragma unroll
        for (int rr = 0; rr < 2; ++rr) {
            const int row = ((o >> 5) << 3) + r0 + rr;
            float* gp = mid + base + row * 256 + col;
            *(float4*)gp       = make_float4(pv[rr][0], pv[rr][1], pv[rr][2], pv[rr][3]);
            *(float4*)(gp + 4) = make_float4(pv[rr][4], pv[rr][5], pv[rr][6], pv[rr][7]);
        }
    }
}

// ---------------------------------------------------------------------------
// Branch 2: reads mid with roll(-4,-4) folded into the load; writes final out
// with roll(+4,+4) folded into the store.
// ---------------------------------------------------------------------------
__global__ __launch_bounds__(256, 2) void k2(
    const float* __restrict__ mid, const float* __restrict__ temp_p,
    const float* __restrict__ qkv_w, const float* __restrict__ qkv_dw,
    const float* __restrict__ proj1_w,
    float* __restrict__ out)
{
    __shared__ __align__(16) float B0[4096], B1[4096], B2[4096], B3[4096], B4[4096];
    const int m = blockIdx.x;
    const int t = threadIdx.x;
    const int plane = m >> 4;   // b*64 + ch
    const int mh2 = m & 15;
    const float* img = mid + ((size_t)plane << 16);

    {   // load shifted strip -> B0 in V layout
        const int yp = t >> 4, xx0 = (t & 15) << 4;
        const int row = (mh2 * 16 + 4 + yp) & 255;
        const int c2b = (yp >> 3) << 5;
        const int ir  = (yp & 7) << 3;
#pragma unroll
        for (int k = 0; k < 4; ++k) {
            const int cc = (xx0 + 4 + 4 * k) & 255;   // 16B aligned, within row
            float4 a = *(const float4*)(img + row * 256 + cc);
            const int xx = xx0 + 4 * k;
            const int off = (c2b + (xx >> 3)) * 64 + ir + (xx & 7);
            *(float4*)(B0 + off) = a;
        }
    }
    __syncthreads();
    mm64(qkv_w + 128 * 64, B0, B1, t);            // tempV
    __syncthreads();
    dw3x3<false>(B1, qkv_dw + 128 * 9, B2, t);    // V -> B2
    mm64(qkv_w, B0, B3, t);                       // tempQ -> B3
    __syncthreads();
    dw3x3<false>(B3, qkv_dw, B1, t);              // Q -> B1 (tempV dead)
    mm64(qkv_w + 64 * 64, B0, B4, t);             // tempK -> B4
    __syncthreads();
    dw3x3<true>(B4, qkv_dw + 64 * 9, B3, t);      // K^T -> B3 (tempQ dead)
    l2norm_rows(B1, t);
    __syncthreads();
    l2norm_cols(B3, t);
    __syncthreads();
    mm64(B1, B3, B0, t);                          // S -> B0 (input dead)
    __syncthreads();
    softmax_rows(B0, temp_p[0], t);
    __syncthreads();
    mm64(B0, B2, B4, t);                          // O = A @ V -> B4
    __syncthreads();
    float pv[2][8];
    proj3x3(B4, proj1_w, t, pv);
    {   // store with roll(+4,+4): final[(R+4)%256][(col+4)%256]
        const int o = t >> 2, r0 = (t & 3) << 1;
        const int col = (o & 31) << 3;
        float* op = out + ((size_t)plane << 16);
#pragma unroll
        for (int rr = 0; rr < 2; ++rr) {
            const int R = mh2 * 16 + ((o >> 5) << 3) + r0 + rr;
            const int orow = (R + 4) & 255;
            const int cA = col + 4;           // <= 252, stays in row, 16B aligned
            const int cB = (col + 8) & 255;   // wraps to 0 when col == 248
            *(float4*)(op + orow * 256 + cA) = make_float4(pv[rr][0], pv[rr][1], pv[rr][2], pv[rr][3]);
            *(float4*)(op + orow * 256 + cB) = make_float4(pv[rr][4], pv[rr][5], pv[rr][6], pv[rr][7]);
        }
    }
}

extern "C" void kernel_launch(void* const* d_in, const int* in_sizes, int n_in,
                              void* d_out, int out_size, void* d_ws, size_t ws_size,
                              hipStream_t stream)
{
    const float* x       = (const float*)d_in[0];
    const float* xf      = (const float*)d_in[1];
    const float* temp    = (const float*)d_in[2];
    const float* qk_w    = (const float*)d_in[3];
    const float* qk_dw   = (const float*)d_in[4];
    const float* v_w     = (const float*)d_in[5];
    const float* v_dw    = (const float*)d_in[6];
    const float* proj_w  = (const float*)d_in[7];
    const float* proj1_w = (const float*)d_in[8];
    const float* qkv1_w  = (const float*)d_in[9];
    const float* qkv1_dw = (const float*)d_in[10];
    float* out = (float*)d_out;
    float* mid = (float*)d_ws;   // needs 64 MiB: branch-1 output image (NCHW)

    k1<<<4096, 256, 0, stream>>>(x, xf, temp, qk_w, qk_dw, v_w, v_dw, proj_w, mid);
    k2<<<4096, 256, 0, stream>>>(mid, temp, qkv1_w, qkv1_dw, proj1_w, out);
}

// Round 2
// 350.138 us; speedup vs baseline: 4.2576x; 4.2576x over previous
//
#include <hip/hip_runtime.h>
#include <hip/hip_fp16.h>

typedef short v8s __attribute__((ext_vector_type(8)));
typedef float v4f __attribute__((ext_vector_type(4)));

#define MFMA_B16(a, b, c) __builtin_amdgcn_mfma_f32_16x16x32_bf16((a), (b), (c), 0, 0, 0)

#define XS 72   // bf16 matrix row stride (144B, 16B aligned, conflict-free frags)
#define TS 68   // fp32 temp matrix row stride (272B, 16B aligned)

// fp32 -> bf16 round-to-nearest-even (finite inputs)
__device__ __forceinline__ unsigned short bfr(float x) {
    unsigned u = __float_as_uint(x);
    u += 0x7fffu + ((u >> 16) & 1u);
    return (unsigned short)(u >> 16);
}

// ---------------------------------------------------------------------------
// Stage-1 1x1 conv: D = Wg(64x64, global bf16 row-major) @ X(LDS [p][c] via XB)
// Wave wv computes rows [16wv,16wv+16). D written fp32 to T[row][col] (wave-local rows).
// ---------------------------------------------------------------------------
__device__ __forceinline__ void mm_stage_g(const unsigned short* __restrict__ Ag,
                                           const unsigned short* __restrict__ XB,
                                           float* __restrict__ T,
                                           int wv, int L, int q)
{
    v4f C[4];
#pragma unroll
    for (int nt = 0; nt < 4; ++nt) C[nt] = (v4f){0.f, 0.f, 0.f, 0.f};
#pragma unroll
    for (int kt = 0; kt < 2; ++kt) {
        v8s a = *(const v8s*)(Ag + (16 * wv + L) * 64 + kt * 32 + q * 8);
#pragma unroll
        for (int nt = 0; nt < 4; ++nt) {
            v8s b = *(const v8s*)(XB + (nt * 16 + L) * XS + kt * 32 + q * 8);
            C[nt] = MFMA_B16(a, b, C[nt]);
        }
    }
    const int rowb = 16 * wv + q * 4;
#pragma unroll
    for (int r = 0; r < 4; ++r) {
#pragma unroll
        for (int nt = 0; nt < 4; ++nt)
            T[(rowb + r) * TS + nt * 16 + L] = C[nt][r];
    }
}

// ---------------------------------------------------------------------------
// Depthwise 3x3 (pad=1) on 8x8 tile of channel c = 16wv + (lane>>2), from fp32 T.
// NORM: L2-normalize the 64-pixel channel (4-thread shfl reduce).
// TR=false: write bf16 row-major [c][p]. TR=true: write transposed [p][c].
// ---------------------------------------------------------------------------
template <bool TR, bool NORM>
__device__ __forceinline__ void dw_stage(const float* __restrict__ T,
                                         const float* __restrict__ dwg,
                                         unsigned short* __restrict__ M,
                                         int wv, int lane)
{
    const int c  = 16 * wv + (lane >> 2);
    const int r0 = (lane & 3) << 1;
    float w[9];
#pragma unroll
    for (int k = 0; k < 9; ++k) w[k] = dwg[c * 9 + k];
    float in[4][10];
#pragma unroll
    for (int r = 0; r < 4; ++r) {
        const int rr = r0 - 1 + r;
        in[r][0] = 0.f; in[r][9] = 0.f;
        if ((unsigned)rr < 8u) {
            float4 a = *(const float4*)(T + c * TS + rr * 8);
            float4 b = *(const float4*)(T + c * TS + rr * 8 + 4);
            in[r][1] = a.x; in[r][2] = a.y; in[r][3] = a.z; in[r][4] = a.w;
            in[r][5] = b.x; in[r][6] = b.y; in[r][7] = b.z; in[r][8] = b.w;
        } else {
#pragma unroll
            for (int j = 1; j < 9; ++j) in[r][j] = 0.f;
        }
    }
    float o[2][8];
#pragma unroll
    for (int rr = 0; rr < 2; ++rr)
#pragma unroll
        for (int j = 0; j < 8; ++j) {
            float s;
            s = w[0] * in[rr][j];
            s = fmaf(w[1], in[rr][j + 1], s);
            s = fmaf(w[2], in[rr][j + 2], s);
            s = fmaf(w[3], in[rr + 1][j], s);
            s = fmaf(w[4], in[rr + 1][j + 1], s);
            s = fmaf(w[5], in[rr + 1][j + 2], s);
            s = fmaf(w[6], in[rr + 2][j], s);
            s = fmaf(w[7], in[rr + 2][j + 1], s);
            s = fmaf(w[8], in[rr + 2][j + 2], s);
            o[rr][j] = s;
        }
    if (NORM) {
        float ss = 0.f;
#pragma unroll
        for (int rr = 0; rr < 2; ++rr)
#pragma unroll
            for (int j = 0; j < 8; ++j) ss = fmaf(o[rr][j], o[rr][j], ss);
        ss += __shfl_xor(ss, 1);
        ss += __shfl_xor(ss, 2);
        const float sc = 1.0f / fmaxf(sqrtf(ss), 1e-12f);
#pragma unroll
        for (int rr = 0; rr < 2; ++rr)
#pragma unroll
            for (int j = 0; j < 8; ++j) o[rr][j] *= sc;
    }
    if (TR) {
#pragma unroll
        for (int rr = 0; rr < 2; ++rr)
#pragma unroll
            for (int j = 0; j < 8; ++j)
                M[((r0 + rr) * 8 + j) * XS + c] = bfr(o[rr][j]);
    } else {
#pragma unroll
        for (int rr = 0; rr < 2; ++rr) {
            v8s v;
#pragma unroll
            for (int j = 0; j < 8; ++j) v[j] = (short)bfr(o[rr][j]);
            *(v8s*)(M + c * XS + (r0 + rr) * 8) = v;
        }
    }
}

// 64x64x64 matmul from two LDS bf16 matrices (A rows = wave stripe), D in regs.
__device__ __forceinline__ void mm_lds(const unsigned short* __restrict__ Am,
                                       const unsigned short* __restrict__ Bm,
                                       int wv, int L, int q, v4f C[4])
{
#pragma unroll
    for (int nt = 0; nt < 4; ++nt) C[nt] = (v4f){0.f, 0.f, 0.f, 0.f};
#pragma unroll
    for (int kt = 0; kt < 2; ++kt) {
        v8s a = *(const v8s*)(Am + (16 * wv + L) * XS + kt * 32 + q * 8);
#pragma unroll
        for (int nt = 0; nt < 4; ++nt) {
            v8s b = *(const v8s*)(Bm + (nt * 16 + L) * XS + kt * 32 + q * 8);
            C[nt] = MFMA_B16(a, b, C[nt]);
        }
    }
}

// proj 3x3 (dense 64ch) as 18 K-tiles of MFMA: K order k = tap*64 + c.
// A = Wg global bf16 [o][tap*64+c]; B built from Ot (LDS [p][c]) with spatial shift.
__device__ __forceinline__ void proj_mm(const unsigned short* __restrict__ Wg,
                                        const unsigned short* __restrict__ Ot,
                                        int wv, int L, int q, v4f C[4])
{
#pragma unroll
    for (int nt = 0; nt < 4; ++nt) C[nt] = (v4f){0.f, 0.f, 0.f, 0.f};
    const unsigned short* arow = Wg + (16 * wv + L) * 576;
    const int pc  = L & 7;
    const int prb = L >> 3;
#pragma unroll
    for (int tap = 0; tap < 9; ++tap) {
        const int dy = tap / 3 - 1, dx = tap % 3 - 1;
        const int spc = pc + dx;
        const bool vc = (unsigned)spc < 8u;
#pragma unroll
        for (int half = 0; half < 2; ++half) {
            v8s a = *(const v8s*)(arow + tap * 64 + half * 32 + q * 8);
#pragma unroll
            for (int nt = 0; nt < 4; ++nt) {
                const int spr = nt * 2 + prb + dy;
                v8s b = {0, 0, 0, 0, 0, 0, 0, 0};
                if (vc && (unsigned)spr < 8u)
                    b = *(const v8s*)(Ot + (spr * 8 + spc) * XS + half * 32 + q * 8);
                C[nt] = MFMA_B16(a, b, C[nt]);
            }
        }
    }
}

// softmax over rows held in S[4] C-frags (rows rowb+r, cols L+16nt), write A bf16 to Am.
__device__ __forceinline__ void softmax_to_lds(v4f S[4], float invt,
                                               unsigned short* __restrict__ Am,
                                               int rowb, int L)
{
#pragma unroll
    for (int nt = 0; nt < 4; ++nt) S[nt] *= invt;
#pragma unroll
    for (int r = 0; r < 4; ++r) {
        float mx = fmaxf(fmaxf(S[0][r], S[1][r]), fmaxf(S[2][r], S[3][r]));
        mx = fmaxf(mx, __shfl_xor(mx, 1));
        mx = fmaxf(mx, __shfl_xor(mx, 2));
        mx = fmaxf(mx, __shfl_xor(mx, 4));
        mx = fmaxf(mx, __shfl_xor(mx, 8));
        float e0 = __expf(S[0][r] - mx);
        float e1 = __expf(S[1][r] - mx);
        float e2 = __expf(S[2][r] - mx);
        float e3 = __expf(S[3][r] - mx);
        float sm = e0 + e1 + e2 + e3;
        sm += __shfl_xor(sm, 1);
        sm += __shfl_xor(sm, 2);
        sm += __shfl_xor(sm, 4);
        sm += __shfl_xor(sm, 8);
        const float ri = 1.0f / sm;
        Am[(rowb + r) * XS + L +  0] = bfr(e0 * ri);
        Am[(rowb + r) * XS + L + 16] = bfr(e1 * ri);
        Am[(rowb + r) * XS + L + 32] = bfr(e2 * ri);
        Am[(rowb + r) * XS + L + 48] = bfr(e3 * ri);
    }
}

// ---------------------------------------------------------------------------
// Weight prep: fp32 -> bf16; proj weights permuted [o][c][tap] -> [o][tap*64+c].
// ---------------------------------------------------------------------------
__global__ void prep(const float* __restrict__ qk_w, const float* __restrict__ v_w,
                     const float* __restrict__ qkv_w, const float* __restrict__ pw0,
                     const float* __restrict__ pw1, unsigned short* __restrict__ Wb)
{
    int i = blockIdx.x * 256 + threadIdx.x;   // 0..98303
    float v;
    if (i < 8192) v = qk_w[i];
    else if (i < 12288) v = v_w[i - 8192];
    else if (i < 24576) v = qkv_w[i - 12288];
    else {
        int j = i - 24576;
        const float* s = pw0;
        if (j >= 36864) { s = pw1; j -= 36864; }
        const int o = j / 576, kk = j % 576;
        const int tap = kk >> 6, c = kk & 63;
        v = s[o * 576 + c * 9 + tap];
    }
    Wb[i] = bfr(v);
}

// ---------------------------------------------------------------------------
// Branch 1: window n = contiguous 4096-float strip. Writes mid (fp16, NCHW strips).
// ---------------------------------------------------------------------------
__global__ __launch_bounds__(256, 3) void k1(
    const float* __restrict__ x, const float* __restrict__ xf,
    const float* __restrict__ temp_p,
    const float* __restrict__ qk_dw, const float* __restrict__ v_dw,
    const unsigned short* __restrict__ Wqk, const unsigned short* __restrict__ Wv,
    const unsigned short* __restrict__ Wp0,
    __half* __restrict__ midh)
{
    __shared__ unsigned short XB[64 * XS];
    __shared__ float T[64 * TS];
    __shared__ unsigned short M0[64 * XS], M1[64 * XS], M2[64 * XS];

    const int t = threadIdx.x, n = blockIdx.x;
    const int lane = t & 63, wv = t >> 6, L = lane & 15, q = lane >> 4;
    const int rowb = 16 * wv + q * 4;
    const size_t base = (size_t)n << 12;
    const float invt = 1.0f / temp_p[0];

    const int yp = t >> 4, xx0 = (t & 15) << 4;
    const int c2b = (yp >> 3) << 5, ir = (yp & 7) << 3;

    {   // load xf strip -> XB as [p][c] bf16
        const float* src = xf + base + yp * 256 + xx0;
#pragma unroll
        for (int k = 0; k < 4; ++k) {
            float4 a = *(const float4*)(src + 4 * k);
            const int xx = xx0 + 4 * k;
            const int c = c2b + (xx >> 3), pb = ir + (xx & 7);
            XB[(pb + 0) * XS + c] = bfr(a.x);
            XB[(pb + 1) * XS + c] = bfr(a.y);
            XB[(pb + 2) * XS + c] = bfr(a.z);
            XB[(pb + 3) * XS + c] = bfr(a.w);
        }
    }
    __syncthreads();
    mm_stage_g(Wqk, XB, T, wv, L, q);                 // tempQ
    __syncthreads();
    dw_stage<false, true>(T, qk_dw, M0, wv, lane);    // Qhat -> M0 [c][p]
    __syncthreads();
    mm_stage_g(Wqk + 4096, XB, T, wv, L, q);          // tempK
    __syncthreads();
    dw_stage<false, true>(T, qk_dw + 576, M1, wv, lane); // Khat -> M1 [c][p]
    __syncthreads();                                  // M1 ready, XB free

    // issue x strip loads (overlap with S/softmax)
    float4 rx[4];
    {
        const float* src = x + base + yp * 256 + xx0;
#pragma unroll
        for (int k = 0; k < 4; ++k) rx[k] = *(const float4*)(src + 4 * k);
    }
    v4f S[4];
    mm_lds(M0, M1, wv, L, q, S);                      // S = Qhat @ Khat^T
    softmax_to_lds(S, invt, M0, rowb, L);             // A -> M0 (wave-local rows)
    {   // x -> XB
#pragma unroll
        for (int k = 0; k < 4; ++k) {
            const int xx = xx0 + 4 * k;
            const int c = c2b + (xx >> 3), pb = ir + (xx & 7);
            XB[(pb + 0) * XS + c] = bfr(rx[k].x);
            XB[(pb + 1) * XS + c] = bfr(rx[k].y);
            XB[(pb + 2) * XS + c] = bfr(rx[k].z);
            XB[(pb + 3) * XS + c] = bfr(rx[k].w);
        }
    }
    __syncthreads();
    mm_stage_g(Wv, XB, T, wv, L, q);                  // tempV
    __syncthreads();
    dw_stage<true, false>(T, v_dw, M2, wv, lane);     // V^T -> M2 [p][c]
    __syncthreads();
    v4f O[4];
    mm_lds(M0, M2, wv, L, q, O);                      // O = A @ V
#pragma unroll
    for (int nt = 0; nt < 4; ++nt)
#pragma unroll
        for (int r = 0; r < 4; ++r)
            M1[(L + 16 * nt) * XS + (rowb + r)] = bfr(O[nt][r]);   // O^T -> M1
    __syncthreads();
    v4f C[4];
    proj_mm(Wp0, M1, wv, L, q, C);
#pragma unroll
    for (int nt = 0; nt < 4; ++nt)
#pragma unroll
        for (int r = 0; r < 4; ++r) {
            const int o = rowb + r, p = L + 16 * nt;
            const int yy = ((o >> 5) << 3) + (p >> 3);
            const int xp = ((o & 31) << 3) + (p & 7);
            midh[base + yy * 256 + xp] = __float2half(C[nt][r]);
        }
}

// ---------------------------------------------------------------------------
// Branch 2: reads mid (fp16) with roll(-4,-4); writes out fp32 with roll(+4,+4).
// ---------------------------------------------------------------------------
__global__ __launch_bounds__(256, 3) void k2(
    const __half* __restrict__ midh, const float* __restrict__ temp_p,
    const float* __restrict__ qkv_dw,
    const unsigned short* __restrict__ Wqkv, const unsigned short* __restrict__ Wp1,
    float* __restrict__ out)
{
    __shared__ unsigned short XB[64 * XS];
    __shared__ float T[64 * TS];
    __shared__ unsigned short M0[64 * XS], M1[64 * XS], M2[64 * XS];

    const int t = threadIdx.x, m = blockIdx.x;
    const int lane = t & 63, wv = t >> 6, L = lane & 15, q = lane >> 4;
    const int rowb = 16 * wv + q * 4;
    const int plane = m >> 4, mh2 = m & 15;
    const __half* img = midh + ((size_t)plane << 16);
    const float invt = 1.0f / temp_p[0];

    {   // shifted strip -> XB [p][c] bf16
        const int yp = t >> 4, xx0 = (t & 15) << 4;
        const int row = (mh2 * 16 + 4 + yp) & 255;
        const int c2b = (yp >> 3) << 5, ir = (yp & 7) << 3;
#pragma unroll
        for (int k = 0; k < 4; ++k) {
            const int cc = (xx0 + 4 + 4 * k) & 255;
            const __half2* hp = (const __half2*)(img + row * 256 + cc);
            __half2 h0 = hp[0], h1 = hp[1];
            const int xx = xx0 + 4 * k;
            const int c = c2b + (xx >> 3), pb = ir + (xx & 7);
            XB[(pb + 0) * XS + c] = bfr(__half2float(h0.x));
            XB[(pb + 1) * XS + c] = bfr(__half2float(h0.y));
            XB[(pb + 2) * XS + c] = bfr(__half2float(h1.x));
            XB[(pb + 3) * XS + c] = bfr(__half2float(h1.y));
        }
    }
    __syncthreads();
    mm_stage_g(Wqkv, XB, T, wv, L, q);
    __syncthreads();
    dw_stage<false, true>(T, qkv_dw, M0, wv, lane);       // Qhat
    __syncthreads();
    mm_stage_g(Wqkv + 4096, XB, T, wv, L, q);
    __syncthreads();
    dw_stage<false, true>(T, qkv_dw + 576, M1, wv, lane); // Khat
    __syncthreads();
    mm_stage_g(Wqkv + 8192, XB, T, wv, L, q);
    __syncthreads();
    dw_stage<true, false>(T, qkv_dw + 1152, M2, wv, lane); // V^T
    __syncthreads();
    v4f S[4];
    mm_lds(M0, M1, wv, L, q, S);
    softmax_to_lds(S, invt, M0, rowb, L);
    __syncthreads();
    v4f O[4];
    mm_lds(M0, M2, wv, L, q, O);
#pragma unroll
    for (int nt = 0; nt < 4; ++nt)
#pragma unroll
        for (int r = 0; r < 4; ++r)
            M1[(L + 16 * nt) * XS + (rowb + r)] = bfr(O[nt][r]);
    __syncthreads();
    v4f C[4];
    proj_mm(Wp1, M1, wv, L, q, C);
    float* op = out + ((size_t)plane << 16);
#pragma unroll
    for (int nt = 0; nt < 4; ++nt)
#pragma unroll
        for (int r = 0; r < 4; ++r) {
            const int o = rowb + r, p = L + 16 * nt;
            const int R = mh2 * 16 + ((o >> 5) << 3) + (p >> 3);
            const int orow = (R + 4) & 255;
            const int ocol = ((o & 31) * 8 + (p & 7) + 4) & 255;
            op[orow * 256 + ocol] = C[nt][r];
        }
}

extern "C" void kernel_launch(void* const* d_in, const int* in_sizes, int n_in,
                              void* d_out, int out_size, void* d_ws, size_t ws_size,
                              hipStream_t stream)
{
    const float* x       = (const float*)d_in[0];
    const float* xf      = (const float*)d_in[1];
    const float* temp    = (const float*)d_in[2];
    const float* qk_w    = (const float*)d_in[3];
    const float* qk_dw   = (const float*)d_in[4];
    const float* v_w     = (const float*)d_in[5];
    const float* v_dw    = (const float*)d_in[6];
    const float* proj_w  = (const float*)d_in[7];
    const float* proj1_w = (const float*)d_in[8];
    const float* qkv1_w  = (const float*)d_in[9];
    const float* qkv1_dw = (const float*)d_in[10];
    float* out = (float*)d_out;

    __half* midh = (__half*)d_ws;                                   // 33554432 B
    unsigned short* Wb = (unsigned short*)((char*)d_ws + 33554432); // 196608 B

    prep<<<384, 256, 0, stream>>>(qk_w, v_w, qkv1_w, proj_w, proj1_w, Wb);
    k1<<<4096, 256, 0, stream>>>(x, xf, temp, qk_dw, v_dw,
                                 Wb, Wb + 8192, Wb + 24576, midh);
    k2<<<4096, 256, 0, stream>>>(midh, temp, qkv1_dw,
                                 Wb + 12288, Wb + 61440, out);
}

// Round 3
// 292.472 us; speedup vs baseline: 5.0971x; 1.1972x over previous
//
#include <hip/hip_runtime.h>

typedef short v8s __attribute__((ext_vector_type(8)));
typedef float v4f __attribute__((ext_vector_type(4)));
typedef unsigned short u16;

#define MFMA_B16(a, b, c) __builtin_amdgcn_mfma_f32_16x16x32_bf16((a), (b), (c), 0, 0, 0)
#define XS 72   // row stride in 16-bit elems (144 B, 16B-aligned rows)

// fp32 -> bf16 round-to-nearest-even
__device__ __forceinline__ u16 bfr(float x) {
    unsigned u = __float_as_uint(x);
    u += 0x7fffu + ((u >> 16) & 1u);
    return (u16)(u >> 16);
}
__device__ __forceinline__ u16 f16r(float x) {
    _Float16 h = (_Float16)x; u16 u; __builtin_memcpy(&u, &h, 2); return u;
}
__device__ __forceinline__ float f16f(u16 u) {
    _Float16 h; __builtin_memcpy(&h, &u, 2); return (float)h;
}

// ---------------------------------------------------------------------------
// Stage-1 1x1 conv: A = 64x64 bf16 weights (global, row-major), B = XB LDS
// bf16 [p][c]. Wave wv -> output rows [16wv,16wv+16). Writes fp16 [c][p] to M.
// ---------------------------------------------------------------------------
__device__ __forceinline__ void mm_stage(const u16* __restrict__ Ag,
                                         const u16* __restrict__ XB,
                                         u16* __restrict__ M,
                                         int wv, int L, int q)
{
    v4f C[4];
#pragma unroll
    for (int nt = 0; nt < 4; ++nt) C[nt] = (v4f){0.f, 0.f, 0.f, 0.f};
#pragma unroll
    for (int kt = 0; kt < 2; ++kt) {
        v8s a = *(const v8s*)(Ag + (16 * wv + L) * 64 + kt * 32 + q * 8);
#pragma unroll
        for (int nt = 0; nt < 4; ++nt) {
            v8s b = *(const v8s*)(XB + (nt * 16 + L) * XS + kt * 32 + q * 8);
            C[nt] = MFMA_B16(a, b, C[nt]);
        }
    }
    const int rowb = 16 * wv + 4 * q;
#pragma unroll
    for (int r = 0; r < 4; ++r)
#pragma unroll
        for (int nt = 0; nt < 4; ++nt)
            M[(rowb + r) * XS + nt * 16 + L] = f16r(C[nt][r]);
}

// dw 3x3 input read: channel c, spatial rows r0-1..r0+2 from fp16 [c][p].
__device__ __forceinline__ void dw_read(const u16* __restrict__ M, int c, int r0,
                                        v8s raw[4])
{
#pragma unroll
    for (int r = 0; r < 4; ++r) {
        const int rr = r0 - 1 + r;
        raw[r] = ((unsigned)rr < 8u) ? *(const v8s*)(M + c * XS + rr * 8)
                                     : (v8s){0, 0, 0, 0, 0, 0, 0, 0};
    }
}

// dw 3x3 compute + optional L2-norm + bf16 write.
// TR=false: [c][p] row-major (v8s packed). TR=true: transposed [p][c] scalar.
template <bool TR, bool NORM>
__device__ __forceinline__ void dw_write(const float* __restrict__ dwg,
                                         const v8s raw[4], int c, int r0,
                                         u16* __restrict__ Out)
{
    float w[9];
#pragma unroll
    for (int k = 0; k < 9; ++k) w[k] = dwg[c * 9 + k];
    float in[4][10];
#pragma unroll
    for (int r = 0; r < 4; ++r) {
        in[r][0] = 0.f; in[r][9] = 0.f;
#pragma unroll
        for (int j = 0; j < 8; ++j) in[r][j + 1] = f16f((u16)raw[r][j]);
    }
    float o[2][8];
#pragma unroll
    for (int rr = 0; rr < 2; ++rr)
#pragma unroll
        for (int j = 0; j < 8; ++j) {
            float s;
            s = w[0] * in[rr][j];
            s = fmaf(w[1], in[rr][j + 1], s);
            s = fmaf(w[2], in[rr][j + 2], s);
            s = fmaf(w[3], in[rr + 1][j], s);
            s = fmaf(w[4], in[rr + 1][j + 1], s);
            s = fmaf(w[5], in[rr + 1][j + 2], s);
            s = fmaf(w[6], in[rr + 2][j], s);
            s = fmaf(w[7], in[rr + 2][j + 1], s);
            s = fmaf(w[8], in[rr + 2][j + 2], s);
            o[rr][j] = s;
        }
    if (NORM) {
        float ss = 0.f;
#pragma unroll
        for (int rr = 0; rr < 2; ++rr)
#pragma unroll
            for (int j = 0; j < 8; ++j) ss = fmaf(o[rr][j], o[rr][j], ss);
        ss += __shfl_xor(ss, 1);
        ss += __shfl_xor(ss, 2);
        const float sc = 1.0f / fmaxf(sqrtf(ss), 1e-12f);
#pragma unroll
        for (int rr = 0; rr < 2; ++rr)
#pragma unroll
            for (int j = 0; j < 8; ++j) o[rr][j] *= sc;
    }
    if (TR) {
#pragma unroll
        for (int rr = 0; rr < 2; ++rr)
#pragma unroll
            for (int j = 0; j < 8; ++j)
                Out[((r0 + rr) * 8 + j) * XS + c] = bfr(o[rr][j]);
    } else {
#pragma unroll
        for (int rr = 0; rr < 2; ++rr) {
            v8s v;
#pragma unroll
            for (int j = 0; j < 8; ++j) v[j] = (short)bfr(o[rr][j]);
            *(v8s*)(Out + c * XS + (r0 + rr) * 8) = v;
        }
    }
}

// 64x64x64 D[m][n] = sum_k A[m][k]*B[n][k], both bf16 LDS, wave stripe rows.
__device__ __forceinline__ void mm_lds(const u16* __restrict__ Am,
                                       const u16* __restrict__ Bm,
                                       int wv, int L, int q, v4f C[4])
{
#pragma unroll
    for (int nt = 0; nt < 4; ++nt) C[nt] = (v4f){0.f, 0.f, 0.f, 0.f};
#pragma unroll
    for (int kt = 0; kt < 2; ++kt) {
        v8s a = *(const v8s*)(Am + (16 * wv + L) * XS + kt * 32 + q * 8);
#pragma unroll
        for (int nt = 0; nt < 4; ++nt) {
            v8s b = *(const v8s*)(Bm + (nt * 16 + L) * XS + kt * 32 + q * 8);
            C[nt] = MFMA_B16(a, b, C[nt]);
        }
    }
}

// proj 3x3 dense: A = Wg global bf16 [o][tap*64+c], B from Ot LDS [p][c].
__device__ __forceinline__ void proj_mm(const u16* __restrict__ Wg,
                                        const u16* __restrict__ Ot,
                                        int wv, int L, int q, v4f C[4])
{
#pragma unroll
    for (int nt = 0; nt < 4; ++nt) C[nt] = (v4f){0.f, 0.f, 0.f, 0.f};
    const u16* arow = Wg + (16 * wv + L) * 576;
    const int pc = L & 7;
    const int prb = L >> 3;
#pragma unroll
    for (int tap = 0; tap < 9; ++tap) {
        const int dy = tap / 3 - 1, dx = tap % 3 - 1;
        const int spc = pc + dx;
        const bool vc = (unsigned)spc < 8u;
#pragma unroll
        for (int half = 0; half < 2; ++half) {
            v8s a = *(const v8s*)(arow + tap * 64 + half * 32 + q * 8);
#pragma unroll
            for (int nt = 0; nt < 4; ++nt) {
                const int spr = nt * 2 + prb + dy;
                v8s b = {0, 0, 0, 0, 0, 0, 0, 0};
                if (vc && (unsigned)spr < 8u)
                    b = *(const v8s*)(Ot + (spr * 8 + spc) * XS + half * 32 + q * 8);
                C[nt] = MFMA_B16(a, b, C[nt]);
            }
        }
    }
}

// softmax over rows in S[4] C-frags, write A bf16 to Am (wave-local rows).
__device__ __forceinline__ void softmax_to_lds(v4f S[4], float invt,
                                               u16* __restrict__ Am,
                                               int rowb, int L)
{
#pragma unroll
    for (int nt = 0; nt < 4; ++nt) S[nt] *= invt;
#pragma unroll
    for (int r = 0; r < 4; ++r) {
        float mx = fmaxf(fmaxf(S[0][r], S[1][r]), fmaxf(S[2][r], S[3][r]));
        mx = fmaxf(mx, __shfl_xor(mx, 1));
        mx = fmaxf(mx, __shfl_xor(mx, 2));
        mx = fmaxf(mx, __shfl_xor(mx, 4));
        mx = fmaxf(mx, __shfl_xor(mx, 8));
        float e0 = __expf(S[0][r] - mx);
        float e1 = __expf(S[1][r] - mx);
        float e2 = __expf(S[2][r] - mx);
        float e3 = __expf(S[3][r] - mx);
        float sm = e0 + e1 + e2 + e3;
        sm += __shfl_xor(sm, 1);
        sm += __shfl_xor(sm, 2);
        sm += __shfl_xor(sm, 4);
        sm += __shfl_xor(sm, 8);
        const float ri = 1.0f / sm;
        Am[(rowb + r) * XS + L +  0] = bfr(e0 * ri);
        Am[(rowb + r) * XS + L + 16] = bfr(e1 * ri);
        Am[(rowb + r) * XS + L + 32] = bfr(e2 * ri);
        Am[(rowb + r) * XS + L + 48] = bfr(e3 * ri);
    }
}

// ---------------------------------------------------------------------------
// Weight prep: fp32 -> bf16; proj weights permuted [o][c][tap] -> [o][tap*64+c].
// ---------------------------------------------------------------------------
__global__ void prep(const float* __restrict__ qk_w, const float* __restrict__ v_w,
                     const float* __restrict__ qkv_w, const float* __restrict__ pw0,
                     const float* __restrict__ pw1, u16* __restrict__ Wb)
{
    int i = blockIdx.x * 256 + threadIdx.x;   // 0..98303
    float v;
    if (i < 8192) v = qk_w[i];
    else if (i < 12288) v = v_w[i - 8192];
    else if (i < 24576) v = qkv_w[i - 12288];
    else {
        int j = i - 24576;
        const float* s = pw0;
        if (j >= 36864) { s = pw1; j -= 36864; }
        const int o = j / 576, kk = j % 576;
        const int tap = kk >> 6, c = kk & 63;
        v = s[o * 576 + c * 9 + tap];
    }
    Wb[i] = bfr(v);
}

// ---------------------------------------------------------------------------
// Branch 1. LDS: 4 x 9216 B = 36.9 KB -> 4 blocks/CU.
// ---------------------------------------------------------------------------
__global__ __launch_bounds__(256, 4) void k1(
    const float* __restrict__ x, const float* __restrict__ xf,
    const float* __restrict__ temp_p,
    const float* __restrict__ qk_dw, const float* __restrict__ v_dw,
    const u16* __restrict__ Wqk, const u16* __restrict__ Wv,
    const u16* __restrict__ Wp0,
    u16* __restrict__ midb)
{
    __shared__ u16 B0[64 * XS], B1[64 * XS], B2[64 * XS], B3[64 * XS];
    const int t = threadIdx.x, n = blockIdx.x;
    const int lane = t & 63, wv = t >> 6, L = lane & 15, q = lane >> 4;
    const int rowb = 16 * wv + 4 * q;
    const size_t base = (size_t)n << 12;
    const float invt = 1.0f / temp_p[0];
    const int yp = t >> 4, xx0 = (t & 15) << 4;
    const int c2b = (yp >> 3) << 5, ir = (yp & 7) << 3;
    const int dc = t >> 2, dr0 = (t & 3) << 1;

    float4 rx[4];
    {   // Xf -> B0 bf16 [p][c]; issue X loads into rx
        const float* sf = xf + base + yp * 256 + xx0;
        const float* sx = x  + base + yp * 256 + xx0;
#pragma unroll
        for (int k = 0; k < 4; ++k) {
            float4 a = *(const float4*)(sf + 4 * k);
            rx[k] = *(const float4*)(sx + 4 * k);
            const int xx = xx0 + 4 * k;
            const int c = c2b + (xx >> 3), pb = ir + (xx & 7);
            B0[(pb + 0) * XS + c] = bfr(a.x);
            B0[(pb + 1) * XS + c] = bfr(a.y);
            B0[(pb + 2) * XS + c] = bfr(a.z);
            B0[(pb + 3) * XS + c] = bfr(a.w);
        }
    }
    __syncthreads();                                    // 1
    mm_stage(Wqk,        B0, B1, wv, L, q);             // Qt (fp16)
    mm_stage(Wqk + 4096, B0, B2, wv, L, q);             // Kt (fp16)
    __syncthreads();                                    // 2
    {   // X -> B3 bf16
#pragma unroll
        for (int k = 0; k < 4; ++k) {
            const int xx = xx0 + 4 * k;
            const int c = c2b + (xx >> 3), pb = ir + (xx & 7);
            B3[(pb + 0) * XS + c] = bfr(rx[k].x);
            B3[(pb + 1) * XS + c] = bfr(rx[k].y);
            B3[(pb + 2) * XS + c] = bfr(rx[k].z);
            B3[(pb + 3) * XS + c] = bfr(rx[k].w);
        }
    }
    v8s rawA[4];
    dw_read(B1, dc, dr0, rawA);                         // Qt
    __syncthreads();                                    // 3
    mm_stage(Wv, B3, B0, wv, L, q);                     // Vt (fp16) -> B0
    dw_write<false, true>(qk_dw, rawA, dc, dr0, B1);    // Qhat -> B1
    v8s rawB[4];
    dw_read(B2, dc, dr0, rawB);                         // Kt
    __syncthreads();                                    // 4
    dw_write<false, true>(qk_dw + 576, rawB, dc, dr0, B2);  // Khat -> B2
    dw_read(B0, dc, dr0, rawA);                         // Vt
    dw_write<true, false>(v_dw, rawA, dc, dr0, B3);     // V^T -> B3
    __syncthreads();                                    // 5
    v4f S[4];
    mm_lds(B1, B2, wv, L, q, S);                        // S = Qhat @ Khat^T
    softmax_to_lds(S, invt, B1, rowb, L);               // A -> B1 (own rows)
    __syncthreads();                                    // 6
    v4f O[4];
    mm_lds(B1, B3, wv, L, q, O);                        // O = A @ V
#pragma unroll
    for (int nt = 0; nt < 4; ++nt)
#pragma unroll
        for (int r = 0; r < 4; ++r)
            B2[(L + 16 * nt) * XS + rowb + r] = bfr(O[nt][r]);  // O^T -> B2
    __syncthreads();                                    // 7
    v4f C[4];
    proj_mm(Wp0, B2, wv, L, q, C);
#pragma unroll
    for (int nt = 0; nt < 4; ++nt)
#pragma unroll
        for (int r = 0; r < 4; ++r) {
            const int o = rowb + r, p = L + 16 * nt;
            const int yy = ((o >> 5) << 3) + (p >> 3);
            const int xp = ((o & 31) << 3) + (p & 7);
            midb[base + yy * 256 + xp] = bfr(C[nt][r]);
        }
}

// ---------------------------------------------------------------------------
// Branch 2: reads mid (bf16) with roll(-4,-4); writes fp32 out with roll(+4,+4).
// ---------------------------------------------------------------------------
__global__ __launch_bounds__(256, 4) void k2(
    const u16* __restrict__ midb, const float* __restrict__ temp_p,
    const float* __restrict__ qkv_dw,
    const u16* __restrict__ Wqkv, const u16* __restrict__ Wp1,
    float* __restrict__ out)
{
    __shared__ u16 B0[64 * XS], B1[64 * XS], B2[64 * XS], B3[64 * XS];
    const int t = threadIdx.x, m = blockIdx.x;
    const int lane = t & 63, wv = t >> 6, L = lane & 15, q = lane >> 4;
    const int rowb = 16 * wv + 4 * q;
    const int plane = m >> 4, mh2 = m & 15;
    const u16* img = midb + ((size_t)plane << 16);
    const float invt = 1.0f / temp_p[0];
    const int yp = t >> 4, xx0 = (t & 15) << 4;
    const int c2b = (yp >> 3) << 5, ir = (yp & 7) << 3;
    const int dc = t >> 2, dr0 = (t & 3) << 1;

    {   // shifted strip -> B0 (pure bf16 copy, no conversion)
        const int row = (mh2 * 16 + 4 + yp) & 255;
#pragma unroll
        for (int k = 0; k < 4; ++k) {
            const int cc = (xx0 + 4 + 4 * k) & 255;
            ushort4 a = *(const ushort4*)(img + row * 256 + cc);
            const int xx = xx0 + 4 * k;
            const int c = c2b + (xx >> 3), pb = ir + (xx & 7);
            B0[(pb + 0) * XS + c] = a.x;
            B0[(pb + 1) * XS + c] = a.y;
            B0[(pb + 2) * XS + c] = a.z;
            B0[(pb + 3) * XS + c] = a.w;
        }
    }
    __syncthreads();                                    // 1
    mm_stage(Wqkv,        B0, B1, wv, L, q);            // Qt
    mm_stage(Wqkv + 4096, B0, B2, wv, L, q);            // Kt
    mm_stage(Wqkv + 8192, B0, B3, wv, L, q);            // Vt
    __syncthreads();                                    // 2
    v8s rawV[4];
    dw_read(B3, dc, dr0, rawV);
    dw_write<true, false>(qkv_dw + 1152, rawV, dc, dr0, B0);  // V^T -> B0
    v8s rawQ[4];
    dw_read(B1, dc, dr0, rawQ);
    __syncthreads();                                    // 3
    dw_write<false, true>(qkv_dw, rawQ, dc, dr0, B1);   // Qhat -> B1
    v8s rawK[4];
    dw_read(B2, dc, dr0, rawK);
    __syncthreads();                                    // 4
    dw_write<false, true>(qkv_dw + 576, rawK, dc, dr0, B2);  // Khat -> B2
    __syncthreads();                                    // 5
    v4f S[4];
    mm_lds(B1, B2, wv, L, q, S);
    softmax_to_lds(S, invt, B1, rowb, L);
    __syncthreads();                                    // 6
    v4f O[4];
    mm_lds(B1, B0, wv, L, q, O);                        // O = A @ V
#pragma unroll
    for (int nt = 0; nt < 4; ++nt)
#pragma unroll
        for (int r = 0; r < 4; ++r)
            B3[(L + 16 * nt) * XS + rowb + r] = bfr(O[nt][r]);  // O^T -> B3
    __syncthreads();                                    // 7
    v4f C[4];
    proj_mm(Wp1, B3, wv, L, q, C);
    float* op = out + ((size_t)plane << 16);
#pragma unroll
    for (int nt = 0; nt < 4; ++nt)
#pragma unroll
        for (int r = 0; r < 4; ++r) {
            const int o = rowb + r, p = L + 16 * nt;
            const int R = mh2 * 16 + ((o >> 5) << 3) + (p >> 3);
            const int orow = (R + 4) & 255;
            const int ocol = ((o & 31) * 8 + (p & 7) + 4) & 255;
            op[orow * 256 + ocol] = C[nt][r];
        }
}

extern "C" void kernel_launch(void* const* d_in, const int* in_sizes, int n_in,
                              void* d_out, int out_size, void* d_ws, size_t ws_size,
                              hipStream_t stream)
{
    const float* x       = (const float*)d_in[0];
    const float* xf      = (const float*)d_in[1];
    const float* temp    = (const float*)d_in[2];
    const float* qk_w    = (const float*)d_in[3];
    const float* qk_dw   = (const float*)d_in[4];
    const float* v_w     = (const float*)d_in[5];
    const float* v_dw    = (const float*)d_in[6];
    const float* proj_w  = (const float*)d_in[7];
    const float* proj1_w = (const float*)d_in[8];
    const float* qkv1_w  = (const float*)d_in[9];
    const float* qkv1_dw = (const float*)d_in[10];
    float* out = (float*)d_out;

    u16* midb = (u16*)d_ws;                               // 33554432 B
    u16* Wb   = (u16*)((char*)d_ws + 33554432);           // 196608 B

    prep<<<384, 256, 0, stream>>>(qk_w, v_w, qkv1_w, proj_w, proj1_w, Wb);
    k1<<<4096, 256, 0, stream>>>(x, xf, temp, qk_dw, v_dw,
                                 Wb, Wb + 8192, Wb + 24576, midb);
    k2<<<4096, 256, 0, stream>>>(midb, temp, qkv1_dw,
                                 Wb + 12288, Wb + 61440, out);
}